// Round 2
// baseline (275.060 us; speedup 1.0000x reference)
//
#include <hip/hip_runtime.h>

#define Bb 8
#define Cch 64
#define D1 65536
#define D2 24576
#define NCH1 512
#define CH1 128
#define NCH2 192
#define CH2 128
#define NEGV -1e30f

// ws layout (floats):
//      0: boxNew[32]
//     32: h1[800]               (b*100+j)
//   8192: feat[196608]          (b*24576 + (s*64+c)*128 + bin)
// 204800: p1[NCH1*100*8]        ((c*100+h)*8+b)          -> ends 614400
// 614400: p2[7*NCH2*8*128]      (((k*192+c)*8+b)*128+h)  -> ends 1990656 (~8 MB)

__global__ __launch_bounds__(128) void k_gemm1(const float* __restrict__ x3,
                                               const float* __restrict__ w1,
                                               float* __restrict__ p1) {
    __shared__ float xs[Bb][CH1];
    int c = blockIdx.x, t = threadIdx.x;
    int d0 = c * CH1;
    #pragma unroll
    for (int b = 0; b < Bb; ++b) xs[b][t] = x3[(size_t)b * D1 + d0 + t];
    __syncthreads();
    if (t < 100) {
        float acc[Bb];
        #pragma unroll
        for (int b = 0; b < Bb; ++b) acc[b] = 0.f;
        #pragma unroll 4
        for (int dl = 0; dl < CH1; ++dl) {
            float w = w1[(size_t)(d0 + dl) * 100 + t];
            #pragma unroll
            for (int b = 0; b < Bb; ++b) acc[b] += w * xs[b][dl];
        }
        #pragma unroll
        for (int b = 0; b < Bb; ++b) p1[((size_t)c * 100 + t) * 8 + b] = acc[b];
    }
}

__global__ __launch_bounds__(64) void k_red1(const float* __restrict__ p1,
                                             const float* __restrict__ b1,
                                             float* __restrict__ h1) {
    int hb = blockIdx.x;            // h*8+b
    int h = hb >> 3, b = hb & 7;
    int t = threadIdx.x;
    float s = 0.f;
    #pragma unroll 4
    for (int c = t; c < NCH1; c += 64) s += p1[((size_t)c * 100 + h) * 8 + b];
    for (int off = 32; off; off >>= 1) s += __shfl_down(s, off);
    if (t == 0) h1[b * 100 + h] = s + b1[h];
}

__global__ __launch_bounds__(256) void k_tail(const float* __restrict__ h1g,
                                              const float* __restrict__ w2,
                                              const float* __restrict__ b2,
                                              const float* __restrict__ w3,
                                              const float* __restrict__ b3,
                                              float* __restrict__ boxNew) {
    __shared__ float h1s[800], h2s[800], bl[32];
    int t = threadIdx.x;
    for (int i = t; i < 800; i += 256) h1s[i] = h1g[i];
    __syncthreads();
    for (int i = t; i < 800; i += 256) {
        int b = i / 100, j = i % 100;
        float s = b2[j];
        for (int k = 0; k < 100; ++k) s += h1s[b * 100 + k] * w2[k * 100 + j];
        h2s[i] = s;
    }
    __syncthreads();
    if (t < 32) {
        int b = t >> 2, m = t & 3;
        float s = b3[m];
        for (int j = 0; j < 100; ++j) s += h2s[b * 100 + j] * w3[j * 4 + m];
        bl[t] = s;
    }
    __syncthreads();
    if (t < 32) {
        int b = t >> 2, i = t & 3;
        float l0 = bl[b * 4 + 0], l1 = bl[b * 4 + 1];
        float l2 = bl[b * 4 + 2], l3 = bl[b * 4 + 3];
        float v = (i == 0) ? l0 - 0.5f * l2
                : (i == 1) ? l1 - 0.5f * l3
                : (i == 2) ? l0 + 0.5f * l2
                           : l1 + 0.5f * l3;
        boxNew[t] = fminf(fmaxf(v, 0.f), 1.f);
    }
}

__global__ __launch_bounds__(128) void k_roi(const float* __restrict__ x1,
                                             const float* __restrict__ x2,
                                             const float* __restrict__ x3,
                                             const float* __restrict__ boxNew,
                                             float* __restrict__ feat) {
    int bid = blockIdx.x;
    int s = bid >> 9, r = bid & 511;
    int b = r >> 6, c = r & 63;
    const float* x = (s == 0) ? x1 : (s == 1) ? x2 : x3;
    int H = (s == 0) ? 128 : (s == 1) ? 64 : 32;   // square inputs
    float bn0 = boxNew[b * 4 + 0], bn1 = boxNew[b * 4 + 1];
    float bn2 = boxNew[b * 4 + 2], bn3 = boxNew[b * 4 + 3];
    float Hf = (float)H;
    int ix1 = (int)floorf(bn0 * Hf);
    int iy1 = (int)floorf(bn1 * Hf);
    int ix2 = (int)floorf(bn2 * Hf);
    int iy2 = (int)floorf(bn3 * Hf);
    bool valid = (ix1 >= 0) && (iy1 >= 0) && (ix2 < H) && (iy2 < H) &&
                 (ix2 > ix1) && (iy2 > iy1);
    int t = threadIdx.x;
    float res = 0.f;
    if (valid) {
        int hh = iy2 - iy1 + 1, ww = ix2 - ix1 + 1;
        int ph = t >> 3, pw = t & 7;
        int rlo = (ph * hh) >> 4;
        int rhi = min((((ph + 1) * hh) + 15) >> 4, hh);
        int clo = (pw * ww) >> 3;
        int chi = min((((pw + 1) * ww) + 7) >> 3, ww);
        float m = NEGV;
        const float* base = x + (size_t)(b * Cch + c) * H * H;
        for (int rr = rlo; rr < rhi; ++rr) {
            const float* row = base + (size_t)(iy1 + rr) * H + ix1;
            for (int cc = clo; cc < chi; ++cc) m = fmaxf(m, row[cc]);
        }
        if (m > -5e29f) res = m;
    }
    feat[(size_t)b * D2 + (s * 64 + c) * 128 + t] = res;
}

__global__ __launch_bounds__(256) void k_gemm2(const float* __restrict__ feat,
                                               const float* __restrict__ hw1,
                                               float* __restrict__ p2) {
    __shared__ float fs[Bb][CH2];
    __shared__ float red[128][9];
    int bid = blockIdx.x;
    int k = bid / NCH2, c = bid % NCH2;
    int d0 = c * CH2;
    int t = threadIdx.x;
    for (int i = t; i < Bb * CH2; i += 256) {
        int b = i >> 7, dl = i & 127;
        fs[b][dl] = feat[(size_t)b * D2 + d0 + dl];
    }
    __syncthreads();
    int h = t & 127, dd = t >> 7;
    float acc[Bb];
    #pragma unroll
    for (int b = 0; b < Bb; ++b) acc[b] = 0.f;
    const float* wbase = hw1 + ((size_t)k * D2 + d0) * 128 + h;
    #pragma unroll 8
    for (int dl = dd; dl < CH2; dl += 2) {
        float w = wbase[(size_t)dl * 128];
        #pragma unroll
        for (int b = 0; b < Bb; ++b) acc[b] += w * fs[b][dl];
    }
    if (dd == 1) {
        #pragma unroll
        for (int b = 0; b < Bb; ++b) red[h][b] = acc[b];
    }
    __syncthreads();
    if (dd == 0) {
        #pragma unroll
        for (int b = 0; b < Bb; ++b) {
            float v = acc[b] + red[h][b];
            p2[(((size_t)k * NCH2 + c) * 8 + b) * 128 + h] = v;
        }
    }
}

// One block per (k,b): reduce p2 -> hidden row (ReLU), then hidden @ w2 -> out.
__global__ __launch_bounds__(128) void k_out(const float* __restrict__ p2,
                                             const float* __restrict__ hb1,
                                             const float* __restrict__ w2p,
                                             const float* __restrict__ b2p,
                                             const float* __restrict__ w2a,
                                             const float* __restrict__ b2a,
                                             const float* __restrict__ w2ad,
                                             const float* __restrict__ b2ad,
                                             float* __restrict__ out) {
    __shared__ float hid[128];
    int kb = blockIdx.x;            // k*8+b
    int k = kb >> 3, b = kb & 7;
    int t = threadIdx.x;            // t = h in phase 1
    float s = 0.f;
    #pragma unroll 8
    for (int c = 0; c < NCH2; ++c)
        s += p2[(((size_t)k * NCH2 + c) * 8 + b) * 128 + t];
    s += hb1[k * 128 + t];
    hid[t] = fmaxf(s, 0.f);
    __syncthreads();

    const float* w;
    const float* bias;
    int nj, off;
    if (k == 0)      { w = w2p;                    bias = b2p;               nj = 38; off = b * 38; }
    else if (k == 1) { w = w2a;                    bias = b2a;               nj = 25; off = 304 + b * 25; }
    else             { int g = k - 2;
                       w = w2ad + (size_t)g * 128 * 35; bias = b2ad + g * 35; nj = 35;
                       off = 504 + g * 280 + b * 35; }
    if (t < nj) {
        float o = bias[t];
        #pragma unroll 8
        for (int h = 0; h < 128; ++h) o += hid[h] * w[(size_t)h * nj + t];
        out[off + t] = o;
    }
}

extern "C" void kernel_launch(void* const* d_in, const int* in_sizes, int n_in,
                              void* d_out, int out_size, void* d_ws, size_t ws_size,
                              hipStream_t stream) {
    const float* x1   = (const float*)d_in[0];
    const float* x2   = (const float*)d_in[1];
    const float* x3   = (const float*)d_in[2];
    const float* w1   = (const float*)d_in[5];
    const float* b1   = (const float*)d_in[6];
    const float* w2   = (const float*)d_in[7];
    const float* b2   = (const float*)d_in[8];
    const float* w3   = (const float*)d_in[9];
    const float* b3   = (const float*)d_in[10];
    const float* hw1  = (const float*)d_in[11];
    const float* hb1  = (const float*)d_in[12];
    const float* w2p  = (const float*)d_in[13];
    const float* b2p  = (const float*)d_in[14];
    const float* w2a  = (const float*)d_in[15];
    const float* b2a  = (const float*)d_in[16];
    const float* w2ad = (const float*)d_in[17];
    const float* b2ad = (const float*)d_in[18];

    float* ws     = (float*)d_ws;
    float* boxNew = ws;
    float* h1     = ws + 32;
    float* feat   = ws + 8192;
    float* p1     = ws + 204800;
    float* p2     = ws + 614400;

    k_gemm1<<<NCH1, 128, 0, stream>>>(x3, w1, p1);
    k_red1<<<800, 64, 0, stream>>>(p1, b1, h1);
    k_tail<<<1, 256, 0, stream>>>(h1, w2, b2, w3, b3, boxNew);
    k_roi<<<1536, 128, 0, stream>>>(x1, x2, x3, boxNew, feat);
    k_gemm2<<<7 * NCH2, 256, 0, stream>>>(feat, hw1, p2);
    k_out<<<56, 128, 0, stream>>>(p2, hb1, w2p, b2p, w2a, b2a, w2ad, b2ad,
                                  (float*)d_out);
}

// Round 6
// 259.759 us; speedup vs baseline: 1.0589x; 1.0589x over previous
//
#include <hip/hip_runtime.h>

#define Bb 8
#define Cch 64
#define D1 65536
#define D2 24576
#define NCH1 512
#define CH1 128
#define NCH2 192
#define CH2 128
#define NEGV -1e30f

// ws layout (floats):
//      0: boxNew[32]
//     32: h1[800]               (b*100+j)
//   8192: feat[196608]          (b*24576 + (s*64+c)*128 + bin)
// 204800: p1[NCH1*100*8]        ((c*100+h)*8+b)          -> ends 614400
// 614400: p2[7*NCH2*8*128]      (((k*192+c)*8+b)*128+h)  -> ends 1990656 (~8 MB)

__global__ __launch_bounds__(256) void k_gemm1(const float* __restrict__ x3,
                                               const float* __restrict__ w1,
                                               float* __restrict__ p1) {
    __shared__ float xs[Bb][CH1];
    __shared__ float red[CH1][9];
    int c = blockIdx.x, t = threadIdx.x;
    int d0 = c * CH1;
    for (int i = t; i < Bb * CH1; i += 256) {
        int b = i >> 7, r = i & 127;
        xs[b][r] = x3[(size_t)b * D1 + d0 + r];
    }
    __syncthreads();
    int j = t & 127, sub = t >> 7;
    float acc[Bb];
    #pragma unroll
    for (int b = 0; b < Bb; ++b) acc[b] = 0.f;
    if (j < 100) {
        const float* wb = w1 + (size_t)(d0 + sub * 64) * 100 + j;
        #pragma unroll 8
        for (int r0 = 0; r0 < 64; ++r0) {
            float w = wb[(size_t)r0 * 100];
            int r = sub * 64 + r0;
            #pragma unroll
            for (int b = 0; b < Bb; ++b) acc[b] += w * xs[b][r];
        }
    }
    if (sub == 1 && j < 100) {
        #pragma unroll
        for (int b = 0; b < Bb; ++b) red[j][b] = acc[b];
    }
    __syncthreads();
    if (sub == 0 && j < 100) {
        #pragma unroll
        for (int b = 0; b < Bb; ++b)
            p1[((size_t)c * 100 + j) * 8 + b] = acc[b] + red[j][b];
    }
}

// one block per output h (100 blocks); threads = (c0, b) so 8 b's share a 32B segment
__global__ __launch_bounds__(256) void k_red1(const float* __restrict__ p1,
                                              const float* __restrict__ b1,
                                              float* __restrict__ h1) {
    __shared__ float red[4][8];
    int h = blockIdx.x;
    int t = threadIdx.x;
    int b = t & 7, c0 = t >> 3;          // c0 in 0..31
    float s = 0.f;
    #pragma unroll
    for (int i = 0; i < 16; ++i) {
        int c = c0 + 32 * i;
        s += p1[((size_t)c * 100 + h) * 8 + b];
    }
    // within-wave: lanes stride 8 share b
    for (int off = 32; off >= 8; off >>= 1) s += __shfl_down(s, off);
    if ((t & 63) < 8) red[t >> 6][t & 7] = s;
    __syncthreads();
    if (t < 8) {
        float v = red[0][t] + red[1][t] + red[2][t] + red[3][t] + b1[h];
        h1[t * 100 + h] = v;             // h1[b*100+h]
    }
}

__global__ __launch_bounds__(256) void k_tail(const float* __restrict__ h1g,
                                              const float* __restrict__ w2,
                                              const float* __restrict__ b2,
                                              const float* __restrict__ w3,
                                              const float* __restrict__ b3,
                                              float* __restrict__ boxNew) {
    __shared__ float h1s[800], h2s[800], bl[32];
    __shared__ float w2s[10000];
    __shared__ float w3s[400];
    int t = threadIdx.x;
    for (int i = t; i < 10000; i += 256) w2s[i] = w2[i];
    for (int i = t; i < 800; i += 256) h1s[i] = h1g[i];
    for (int i = t; i < 400; i += 256) w3s[i] = w3[i];
    __syncthreads();
    for (int i = t; i < 800; i += 256) {
        int b = i / 100, j = i % 100;
        float s = b2[j];
        #pragma unroll 4
        for (int k = 0; k < 100; ++k) s += h1s[b * 100 + k] * w2s[k * 100 + j];
        h2s[i] = s;
    }
    __syncthreads();
    if (t < 32) {
        int b = t >> 2, m = t & 3;
        float s = b3[m];
        #pragma unroll 4
        for (int j = 0; j < 100; ++j) s += h2s[b * 100 + j] * w3s[j * 4 + m];
        bl[t] = s;
    }
    __syncthreads();
    if (t < 32) {
        int b = t >> 2, i = t & 3;
        float l0 = bl[b * 4 + 0], l1 = bl[b * 4 + 1];
        float l2 = bl[b * 4 + 2], l3 = bl[b * 4 + 3];
        float v = (i == 0) ? l0 - 0.5f * l2
                : (i == 1) ? l1 - 0.5f * l3
                : (i == 2) ? l0 + 0.5f * l2
                           : l1 + 0.5f * l3;
        boxNew[t] = fminf(fmaxf(v, 0.f), 1.f);
    }
}

__global__ __launch_bounds__(128) void k_roi(const float* __restrict__ x1,
                                             const float* __restrict__ x2,
                                             const float* __restrict__ x3,
                                             const float* __restrict__ boxNew,
                                             float* __restrict__ feat) {
    int bid = blockIdx.x;
    int s = bid >> 9, r = bid & 511;
    int b = r >> 6, c = r & 63;
    const float* x = (s == 0) ? x1 : (s == 1) ? x2 : x3;
    int H = (s == 0) ? 128 : (s == 1) ? 64 : 32;   // square inputs
    float bn0 = boxNew[b * 4 + 0], bn1 = boxNew[b * 4 + 1];
    float bn2 = boxNew[b * 4 + 2], bn3 = boxNew[b * 4 + 3];
    float Hf = (float)H;
    int ix1 = (int)floorf(bn0 * Hf);
    int iy1 = (int)floorf(bn1 * Hf);
    int ix2 = (int)floorf(bn2 * Hf);
    int iy2 = (int)floorf(bn3 * Hf);
    bool valid = (ix1 >= 0) && (iy1 >= 0) && (ix2 < H) && (iy2 < H) &&
                 (ix2 > ix1) && (iy2 > iy1);
    int t = threadIdx.x;
    float res = 0.f;
    if (valid) {
        int hh = iy2 - iy1 + 1, ww = ix2 - ix1 + 1;
        int ph = t >> 3, pw = t & 7;
        int rlo = (ph * hh) >> 4;
        int rhi = min((((ph + 1) * hh) + 15) >> 4, hh);
        int clo = (pw * ww) >> 3;
        int chi = min((((pw + 1) * ww) + 7) >> 3, ww);
        float m = NEGV;
        const float* base = x + (size_t)(b * Cch + c) * H * H;
        for (int rr = rlo; rr < rhi; ++rr) {
            const float* row = base + (size_t)(iy1 + rr) * H + ix1;
            for (int cc = clo; cc < chi; ++cc) m = fmaxf(m, row[cc]);
        }
        if (m > -5e29f) res = m;
    }
    feat[(size_t)b * D2 + (s * 64 + c) * 128 + t] = res;
}

__global__ __launch_bounds__(256) void k_gemm2(const float* __restrict__ feat,
                                               const float* __restrict__ hw1,
                                               float* __restrict__ p2) {
    __shared__ float fs[Bb][CH2];        // 4 KB
    __shared__ float red[3][64][17];     // padded, ~13 KB
    int bid = blockIdx.x;
    int k = bid / NCH2, c = bid % NCH2;
    int d0 = c * CH2;
    int t = threadIdx.x;
    for (int i = t; i < Bb * CH2; i += 256) {
        int b = i >> 7, dl = i & 127;
        fs[b][dl] = feat[(size_t)b * D2 + d0 + dl];
    }
    __syncthreads();
    int l = t & 63, sub = t >> 6;        // sub in 0..3
    int h2 = l * 2;
    float accx[Bb], accy[Bb];
    #pragma unroll
    for (int b = 0; b < Bb; ++b) { accx[b] = 0.f; accy[b] = 0.f; }
    const float* wbase = hw1 + ((size_t)k * D2 + d0) * 128 + h2;
    #pragma unroll 8
    for (int i = 0; i < 32; ++i) {
        int dl = sub + 4 * i;
        float2 w = *(const float2*)&wbase[(size_t)dl * 128];
        #pragma unroll
        for (int b = 0; b < Bb; ++b) {
            float f = fs[b][dl];
            accx[b] += w.x * f;
            accy[b] += w.y * f;
        }
    }
    if (sub) {
        #pragma unroll
        for (int b = 0; b < Bb; ++b) {
            red[sub - 1][l][b * 2]     = accx[b];
            red[sub - 1][l][b * 2 + 1] = accy[b];
        }
    }
    __syncthreads();
    if (sub == 0) {
        #pragma unroll
        for (int b = 0; b < Bb; ++b) {
            float vx = accx[b] + red[0][l][b * 2]     + red[1][l][b * 2]     + red[2][l][b * 2];
            float vy = accy[b] + red[0][l][b * 2 + 1] + red[1][l][b * 2 + 1] + red[2][l][b * 2 + 1];
            float2 v = make_float2(vx, vy);
            *(float2*)&p2[(((size_t)k * NCH2 + c) * 8 + b) * 128 + h2] = v;
        }
    }
}

// One block per (k,b): reduce p2 -> hidden row (ReLU), then hidden @ w2 -> out.
__global__ __launch_bounds__(256) void k_out(const float* __restrict__ p2,
                                             const float* __restrict__ hb1,
                                             const float* __restrict__ w2p,
                                             const float* __restrict__ b2p,
                                             const float* __restrict__ w2a,
                                             const float* __restrict__ b2a,
                                             const float* __restrict__ w2ad,
                                             const float* __restrict__ b2ad,
                                             float* __restrict__ out) {
    __shared__ float hid[128];
    __shared__ float red[128];
    int kb = blockIdx.x;            // k*8+b
    int k = kb >> 3, b = kb & 7;
    int t = threadIdx.x;
    int h = t & 127, sub = t >> 7;
    float s = 0.f;
    #pragma unroll 8
    for (int c = sub; c < NCH2; c += 2)
        s += p2[(((size_t)k * NCH2 + c) * 8 + b) * 128 + h];
    if (sub) red[h] = s;
    __syncthreads();
    if (!sub) hid[h] = fmaxf(s + red[h] + hb1[k * 128 + h], 0.f);
    __syncthreads();

    const float* w;
    const float* bias;
    int nj, off;
    if (k == 0)      { w = w2p;                    bias = b2p;               nj = 38; off = b * 38; }
    else if (k == 1) { w = w2a;                    bias = b2a;               nj = 25; off = 304 + b * 25; }
    else             { int g = k - 2;
                       w = w2ad + (size_t)g * 128 * 35; bias = b2ad + g * 35; nj = 35;
                       off = 504 + g * 280 + b * 35; }
    if (t < nj) {
        float o = bias[t];
        #pragma unroll 8
        for (int hh = 0; hh < 128; ++hh) o += hid[hh] * w[(size_t)hh * nj + t];
        out[off + t] = o;
    }
}

extern "C" void kernel_launch(void* const* d_in, const int* in_sizes, int n_in,
                              void* d_out, int out_size, void* d_ws, size_t ws_size,
                              hipStream_t stream) {
    const float* x1   = (const float*)d_in[0];
    const float* x2   = (const float*)d_in[1];
    const float* x3   = (const float*)d_in[2];
    const float* w1   = (const float*)d_in[5];
    const float* b1   = (const float*)d_in[6];
    const float* w2   = (const float*)d_in[7];
    const float* b2   = (const float*)d_in[8];
    const float* w3   = (const float*)d_in[9];
    const float* b3   = (const float*)d_in[10];
    const float* hw1  = (const float*)d_in[11];
    const float* hb1  = (const float*)d_in[12];
    const float* w2p  = (const float*)d_in[13];
    const float* b2p  = (const float*)d_in[14];
    const float* w2a  = (const float*)d_in[15];
    const float* b2a  = (const float*)d_in[16];
    const float* w2ad = (const float*)d_in[17];
    const float* b2ad = (const float*)d_in[18];

    float* ws     = (float*)d_ws;
    float* boxNew = ws;
    float* h1     = ws + 32;
    float* feat   = ws + 8192;
    float* p1     = ws + 204800;
    float* p2     = ws + 614400;

    k_gemm1<<<NCH1, 256, 0, stream>>>(x3, w1, p1);
    k_red1<<<100, 256, 0, stream>>>(p1, b1, h1);
    k_tail<<<1, 256, 0, stream>>>(h1, w2, b2, w3, b3, boxNew);
    k_roi<<<1536, 128, 0, stream>>>(x1, x2, x3, boxNew, feat);
    k_gemm2<<<7 * NCH2, 256, 0, stream>>>(feat, hw1, p2);
    k_out<<<56, 256, 0, stream>>>(p2, hb1, w2p, b2p, w2a, b2a, w2ad, b2ad,
                                  (float*)d_out);
}

// Round 9
// 255.015 us; speedup vs baseline: 1.0786x; 1.0186x over previous
//
#include <hip/hip_runtime.h>

#define Bb 8
#define Cch 64
#define D1 65536
#define D2 24576
#define NCH1 512
#define CH1 128
#define NCH2 192
#define CH2 128
#define NEGV -1e30f

// ws layout (floats):
//      0: boxNew[32]
//     32: h1[800]               (b*100+j)
//   8192: feat[196608]          (b*24576 + (s*64+c)*128 + bin)
// 204800: p1[NCH1*100*8]        ((c*100+h)*8+b)          -> ends 614400
// 614400: p2[7*NCH2*8*128]      (((k*192+c)*8+b)*128+h)  -> ends 1990656 (~8 MB)

__global__ __launch_bounds__(256) void k_gemm1(const float* __restrict__ x3,
                                               const float* __restrict__ w1,
                                               float* __restrict__ p1) {
    __shared__ float xs[Bb][CH1];
    __shared__ float red[CH1][9];
    int c = blockIdx.x, t = threadIdx.x;
    int d0 = c * CH1;
    {   // 256 threads = exactly 8 rows x 32 float4s
        int b = t >> 5, r4 = (t & 31) * 4;
        float4 v = *(const float4*)&x3[(size_t)b * D1 + d0 + r4];
        xs[b][r4] = v.x; xs[b][r4 + 1] = v.y; xs[b][r4 + 2] = v.z; xs[b][r4 + 3] = v.w;
    }
    __syncthreads();
    int j = t & 127, sub = t >> 7;
    float acc[Bb];
    #pragma unroll
    for (int b = 0; b < Bb; ++b) acc[b] = 0.f;
    if (j < 100) {
        const float* wb = w1 + (size_t)(d0 + sub * 64) * 100 + j;
        #pragma unroll 8
        for (int r0 = 0; r0 < 64; ++r0) {
            float w = wb[(size_t)r0 * 100];
            int r = sub * 64 + r0;
            #pragma unroll
            for (int b = 0; b < Bb; ++b) acc[b] += w * xs[b][r];
        }
    }
    if (sub == 1 && j < 100) {
        #pragma unroll
        for (int b = 0; b < Bb; ++b) red[j][b] = acc[b];
    }
    __syncthreads();
    if (sub == 0 && j < 100) {
        #pragma unroll
        for (int b = 0; b < Bb; ++b)
            p1[((size_t)c * 100 + j) * 8 + b] = acc[b] + red[j][b];
    }
}

// one block per output h (100 blocks); threads = (c0, b) so 8 b's share a 32B segment
__global__ __launch_bounds__(256) void k_red1(const float* __restrict__ p1,
                                              const float* __restrict__ b1,
                                              float* __restrict__ h1) {
    __shared__ float red[4][8];
    int h = blockIdx.x;
    int t = threadIdx.x;
    int b = t & 7, c0 = t >> 3;          // c0 in 0..31
    float s = 0.f;
    #pragma unroll
    for (int i = 0; i < 16; ++i) {
        int c = c0 + 32 * i;
        s += p1[((size_t)c * 100 + h) * 8 + b];
    }
    // within-wave: lanes stride 8 share b
    for (int off = 32; off >= 8; off >>= 1) s += __shfl_down(s, off);
    if ((t & 63) < 8) red[t >> 6][t & 7] = s;
    __syncthreads();
    if (t < 8) {
        float v = red[0][t] + red[1][t] + red[2][t] + red[3][t] + b1[h];
        h1[t * 100 + h] = v;             // h1[b*100+h]
    }
}

// one block per batch sample b (8 blocks, 128 threads)
__global__ __launch_bounds__(128) void k_tail(const float* __restrict__ h1g,
                                              const float* __restrict__ w2,
                                              const float* __restrict__ b2,
                                              const float* __restrict__ w3,
                                              const float* __restrict__ b3,
                                              float* __restrict__ boxNew) {
    __shared__ float w2s[10000];
    __shared__ float h1s[100], h2s[100], w3s[400], bl[4];
    int b = blockIdx.x;
    int t = threadIdx.x;
    for (int i = t; i < 10000; i += 128) w2s[i] = w2[i];
    if (t < 100) h1s[t] = h1g[b * 100 + t];
    for (int i = t; i < 400; i += 128) w3s[i] = w3[i];
    __syncthreads();
    if (t < 100) {
        float s = b2[t];
        #pragma unroll 4
        for (int k = 0; k < 100; ++k) s += h1s[k] * w2s[k * 100 + t];
        h2s[t] = s;
    }
    __syncthreads();
    if (t < 4) {
        float s = b3[t];
        #pragma unroll 4
        for (int j = 0; j < 100; ++j) s += h2s[j] * w3s[j * 4 + t];
        bl[t] = s;
    }
    __syncthreads();
    if (t < 4) {
        float l0 = bl[0], l1 = bl[1], l2 = bl[2], l3 = bl[3];
        float v = (t == 0) ? l0 - 0.5f * l2
                : (t == 1) ? l1 - 0.5f * l3
                : (t == 2) ? l0 + 0.5f * l2
                           : l1 + 0.5f * l3;
        boxNew[b * 4 + t] = fminf(fmaxf(v, 0.f), 1.f);
    }
}

__global__ __launch_bounds__(128) void k_roi(const float* __restrict__ x1,
                                             const float* __restrict__ x2,
                                             const float* __restrict__ x3,
                                             const float* __restrict__ boxNew,
                                             float* __restrict__ feat) {
    int bid = blockIdx.x;
    int s = bid >> 9, r = bid & 511;
    int b = r >> 6, c = r & 63;
    const float* x = (s == 0) ? x1 : (s == 1) ? x2 : x3;
    int H = (s == 0) ? 128 : (s == 1) ? 64 : 32;   // square inputs
    float bn0 = boxNew[b * 4 + 0], bn1 = boxNew[b * 4 + 1];
    float bn2 = boxNew[b * 4 + 2], bn3 = boxNew[b * 4 + 3];
    float Hf = (float)H;
    int ix1 = (int)floorf(bn0 * Hf);
    int iy1 = (int)floorf(bn1 * Hf);
    int ix2 = (int)floorf(bn2 * Hf);
    int iy2 = (int)floorf(bn3 * Hf);
    bool valid = (ix1 >= 0) && (iy1 >= 0) && (ix2 < H) && (iy2 < H) &&
                 (ix2 > ix1) && (iy2 > iy1);
    int t = threadIdx.x;
    float res = 0.f;
    if (valid) {
        int hh = iy2 - iy1 + 1, ww = ix2 - ix1 + 1;
        int ph = t >> 3, pw = t & 7;
        int rlo = (ph * hh) >> 4;
        int rhi = min((((ph + 1) * hh) + 15) >> 4, hh);
        int clo = (pw * ww) >> 3;
        int chi = min((((pw + 1) * ww) + 7) >> 3, ww);
        float m = NEGV;
        const float* base = x + (size_t)(b * Cch + c) * H * H;
        for (int rr = rlo; rr < rhi; ++rr) {
            const float* row = base + (size_t)(iy1 + rr) * H + ix1;
            for (int cc = clo; cc < chi; ++cc) m = fmaxf(m, row[cc]);
        }
        if (m > -5e29f) res = m;
    }
    feat[(size_t)b * D2 + (s * 64 + c) * 128 + t] = res;
}

__global__ __launch_bounds__(256) void k_gemm2(const float* __restrict__ feat,
                                               const float* __restrict__ hw1,
                                               float* __restrict__ p2) {
    __shared__ float fs[Bb][CH2];        // 4 KB
    __shared__ float red[3][64][17];     // padded, ~13 KB
    int bid = blockIdx.x;
    int k = bid / NCH2, c = bid % NCH2;
    int d0 = c * CH2;
    int t = threadIdx.x;
    for (int i = t; i < Bb * CH2; i += 256) {
        int b = i >> 7, dl = i & 127;
        fs[b][dl] = feat[(size_t)b * D2 + d0 + dl];
    }
    __syncthreads();
    int l = t & 63, sub = t >> 6;        // sub in 0..3
    int h2 = l * 2;
    float accx[Bb], accy[Bb];
    #pragma unroll
    for (int b = 0; b < Bb; ++b) { accx[b] = 0.f; accy[b] = 0.f; }
    const float* wbase = hw1 + ((size_t)k * D2 + d0) * 128 + h2;
    #pragma unroll 8
    for (int i = 0; i < 32; ++i) {
        int dl = sub + 4 * i;
        float2 w = *(const float2*)&wbase[(size_t)dl * 128];
        #pragma unroll
        for (int b = 0; b < Bb; ++b) {
            float f = fs[b][dl];
            accx[b] += w.x * f;
            accy[b] += w.y * f;
        }
    }
    if (sub) {
        #pragma unroll
        for (int b = 0; b < Bb; ++b) {
            red[sub - 1][l][b * 2]     = accx[b];
            red[sub - 1][l][b * 2 + 1] = accy[b];
        }
    }
    __syncthreads();
    if (sub == 0) {
        #pragma unroll
        for (int b = 0; b < Bb; ++b) {
            float vx = accx[b] + red[0][l][b * 2]     + red[1][l][b * 2]     + red[2][l][b * 2];
            float vy = accy[b] + red[0][l][b * 2 + 1] + red[1][l][b * 2 + 1] + red[2][l][b * 2 + 1];
            float2 v = make_float2(vx, vy);
            *(float2*)&p2[(((size_t)k * NCH2 + c) * 8 + b) * 128 + h2] = v;
        }
    }
}

// One block per (k,b): reduce p2 -> hidden row (ReLU), then hidden @ w2 -> out.
__global__ __launch_bounds__(256) void k_out(const float* __restrict__ p2,
                                             const float* __restrict__ hb1,
                                             const float* __restrict__ w2p,
                                             const float* __restrict__ b2p,
                                             const float* __restrict__ w2a,
                                             const float* __restrict__ b2a,
                                             const float* __restrict__ w2ad,
                                             const float* __restrict__ b2ad,
                                             float* __restrict__ out) {
    __shared__ float hid[128];
    __shared__ float red[128];
    int kb = blockIdx.x;            // k*8+b
    int k = kb >> 3, b = kb & 7;
    int t = threadIdx.x;
    int h = t & 127, sub = t >> 7;
    float s = 0.f;
    #pragma unroll 8
    for (int c = sub; c < NCH2; c += 2)
        s += p2[(((size_t)k * NCH2 + c) * 8 + b) * 128 + h];
    if (sub) red[h] = s;
    __syncthreads();
    if (!sub) hid[h] = fmaxf(s + red[h] + hb1[k * 128 + h], 0.f);
    __syncthreads();

    const float* w;
    const float* bias;
    int nj, off;
    if (k == 0)      { w = w2p;                    bias = b2p;               nj = 38; off = b * 38; }
    else if (k == 1) { w = w2a;                    bias = b2a;               nj = 25; off = 304 + b * 25; }
    else             { int g = k - 2;
                       w = w2ad + (size_t)g * 128 * 35; bias = b2ad + g * 35; nj = 35;
                       off = 504 + g * 280 + b * 35; }
    if (t < nj) {
        float o = bias[t];
        #pragma unroll 8
        for (int hh = 0; hh < 128; ++hh) o += hid[hh] * w[(size_t)hh * nj + t];
        out[off + t] = o;
    }
}

extern "C" void kernel_launch(void* const* d_in, const int* in_sizes, int n_in,
                              void* d_out, int out_size, void* d_ws, size_t ws_size,
                              hipStream_t stream) {
    const float* x1   = (const float*)d_in[0];
    const float* x2   = (const float*)d_in[1];
    const float* x3   = (const float*)d_in[2];
    const float* w1   = (const float*)d_in[5];
    const float* b1   = (const float*)d_in[6];
    const float* w2   = (const float*)d_in[7];
    const float* b2   = (const float*)d_in[8];
    const float* w3   = (const float*)d_in[9];
    const float* b3   = (const float*)d_in[10];
    const float* hw1  = (const float*)d_in[11];
    const float* hb1  = (const float*)d_in[12];
    const float* w2p  = (const float*)d_in[13];
    const float* b2p  = (const float*)d_in[14];
    const float* w2a  = (const float*)d_in[15];
    const float* b2a  = (const float*)d_in[16];
    const float* w2ad = (const float*)d_in[17];
    const float* b2ad = (const float*)d_in[18];

    float* ws     = (float*)d_ws;
    float* boxNew = ws;
    float* h1     = ws + 32;
    float* feat   = ws + 8192;
    float* p1     = ws + 204800;
    float* p2     = ws + 614400;

    k_gemm1<<<NCH1, 256, 0, stream>>>(x3, w1, p1);
    k_red1<<<100, 256, 0, stream>>>(p1, b1, h1);
    k_tail<<<8, 128, 0, stream>>>(h1, w2, b2, w3, b3, boxNew);
    k_roi<<<1536, 128, 0, stream>>>(x1, x2, x3, boxNew, feat);
    k_gemm2<<<7 * NCH2, 256, 0, stream>>>(feat, hw1, p2);
    k_out<<<56, 256, 0, stream>>>(p2, hb1, w2p, b2p, w2a, b2a, w2ad, b2ad,
                                  (float*)d_out);
}